// Round 13
// baseline (333.573 us; speedup 1.0000x reference)
//
#include <hip/hip_runtime.h>
#include <math.h>

#define BSZ 2
#define SEQ 1024
#define DM  1024          // d_model
#define DI  2048          // d_inner
#define DS  16            // d_state
#define DC  4             // d_conv
#define DR  64            // dt_rank
#define NDBL 96           // DR + 2*DS
#define NC  32            // scan chunks
#define LC  32            // SEQ / NC
#define MM  (BSZ * SEQ)   // 2048 rows

typedef unsigned short u16;
typedef __bf16 bf16x8 __attribute__((ext_vector_type(8)));
typedef float  f32x4  __attribute__((ext_vector_type(4)));

// ---- segment sizes (float4 units) and weight-block offsets (u16 units) ----
constexpr int N4_X   = MM * DM / 4;          //   524,288
constexpr int N4_MW  = DM * 2 * DM / 4;      //   524,288
constexpr int N4_IN  = 2 * DI * DM / 4;      // 1,048,576
constexpr int N4_XP  = NDBL * DI / 4;        //    49,152
constexpr int N4_DT  = DI * DR / 4;          //    32,768
constexpr int N4_OUT = DM * DI / 4;          //   524,288
constexpr int N4_TOTAL = N4_X + N4_MW + 2 * (N4_IN + N4_XP + N4_DT + N4_OUT);
constexpr size_t O_XP  = (size_t)2 * DI * DM;            // 4,194,304
constexpr size_t O_DT  = O_XP + (size_t)NDBL * DI;       // 4,390,912
constexpr size_t O_OUT = O_DT + (size_t)DI * DR;         // 4,521,984
constexpr size_t WBF_SZ = O_OUT + (size_t)DM * DI;       // 6,619,136 u16 per dir

__device__ __forceinline__ u16 f2b(float f) {
    unsigned int u = __float_as_uint(f);
    unsigned int r = (u + 0x7fffu + ((u >> 16) & 1u)) >> 16;
    return (u16)r;
}
__device__ __forceinline__ float b2f(u16 h) {
    return __uint_as_float(((unsigned int)h) << 16);
}

__device__ __forceinline__ void stf(float* p, size_t i, float v) { p[i] = v; }
__device__ __forceinline__ void stf(u16* p, size_t i, float v)   { p[i] = f2b(v); }

// ---- fast transcendentals ----
__device__ __forceinline__ float fexp(float x)  { return __expf(x); }
__device__ __forceinline__ float frcp(float x)  { return __builtin_amdgcn_rcpf(x); }
__device__ __forceinline__ float silu_fast(float x) {
    return x * frcp(1.f + fexp(-x));
}
__device__ __forceinline__ float softplus_fast(float x) {
    return (x > 15.f) ? x : __logf(1.f + fexp(x));
}

// ---- async global->LDS, 16B/lane; dest = wave-uniform base + lane*16 ----
__device__ __forceinline__ void async16(const u16* g, u16* l) {
    __builtin_amdgcn_global_load_lds(
        (const __attribute__((address_space(1))) void*)g,
        (__attribute__((address_space(3))) void*)l, 16, 0, 0);
}

// XOR-swizzle: 16B-slot for (row, 8-elem chunk j) — 2-way bank aliasing only.
__device__ __forceinline__ int lds_slot(int row, int j) {
    return row * 4 + ((j + (row >> 1)) & 3);
}

// bijective XCD-chunking remap (m204): physical dispatch id p -> logical work
// id such that XCD (p%8) owns a contiguous logical chunk.
__device__ __forceinline__ int xcd_swz(int flat, int nwg) {
    int q = nwg >> 3, r = nwg & 7;
    int x = flat & 7, i = flat >> 3;
    return (x < r ? x * (q + 1) : r * (q + 1) + (x - r) * q) + i;
}

// ---- staging helper for fp32 A: 8 floats -> 8 bf16 at LDS slot ----
__device__ __forceinline__ void stage8f(const float* p, u16* d) {
    float4 v0 = *(const float4*)p;
    float4 v1 = *(const float4*)(p + 4);
    ushort4 a; a.x = f2b(v0.x); a.y = f2b(v0.y); a.z = f2b(v0.z); a.w = f2b(v0.w);
    ushort4 b; b.x = f2b(v1.x); b.y = f2b(v1.y); b.z = f2b(v1.z); b.w = f2b(v1.w);
    *(ushort4*)d = a;
    *(ushort4*)(d + 4) = b;
}

// ---- stage a [LC x 256] u16 tile (row stride = ld u16) into linear LDS ----
__device__ __forceinline__ void stage_tile256(
    const u16* __restrict__ g, int row0, int ld, int e0, u16* lds, int t)
{
    const int wv = t >> 6, ln = t & 63;
    #pragma unroll
    for (int iss = 0; iss < 4; iss++) {
        int row = wv * 8 + iss * 2;
        const u16* src = g + (size_t)(row0 + row + (ln >> 5)) * ld
                       + e0 + (ln & 31) * 8;
        async16(src, &lds[row * 256]);
    }
}

// ---- one-shot fp32->bf16 convert of x, merge_w, and both dirs' weights ----
__global__ __launch_bounds__(256) void cvt_all_kernel(
    const float* __restrict__ s0, const float* __restrict__ s1,
    const float* __restrict__ s2, const float* __restrict__ s3,
    const float* __restrict__ s4, const float* __restrict__ s5,
    const float* __restrict__ s6, const float* __restrict__ s7,
    const float* __restrict__ s8, const float* __restrict__ s9,
    u16* __restrict__ d0, u16* __restrict__ d1, u16* __restrict__ d2,
    u16* __restrict__ d3, u16* __restrict__ d4, u16* __restrict__ d5,
    u16* __restrict__ d6, u16* __restrict__ d7, u16* __restrict__ d8,
    u16* __restrict__ d9)
{
    int i = blockIdx.x * 256 + threadIdx.x;
    const float* s; u16* d;
    if (i < N4_X) { s = s0; d = d0; }                    // x
    else if ((i -= N4_X) < N4_MW) { s = s1; d = d1; }    // merge_w
    else if ((i -= N4_MW) < N4_IN) { s = s2; d = d2; }   // in0
    else if ((i -= N4_IN) < N4_XP) { s = s3; d = d3; }   // xp0
    else if ((i -= N4_XP) < N4_DT) { s = s4; d = d4; }   // dt0
    else if ((i -= N4_DT) < N4_OUT) { s = s5; d = d5; }  // out0
    else if ((i -= N4_OUT) < N4_IN) { s = s6; d = d6; }  // in1
    else if ((i -= N4_IN) < N4_XP) { s = s7; d = d7; }   // xp1
    else if ((i -= N4_XP) < N4_DT) { s = s8; d = d8; }   // dt1
    else if ((i -= N4_DT) < N4_OUT) { s = s9; d = d9; }  // out1
    else return;
    float4 v = ((const float4*)s)[i];
    ushort4 o; o.x = f2b(v.x); o.y = f2b(v.y); o.z = f2b(v.z); o.w = f2b(v.w);
    ((ushort4*)d)[i] = o;
}

// ===========================================================================
// 256x256-tile 8-phase GEMM (HK-style schedule) for step 1. See R5 lesson:
// this beats the BN=128 2-phase loop at this shape (FETCH 24.6 vs 69.7 MB).
// ===========================================================================
__global__ __launch_bounds__(512) void gemm256_dual(
    const u16* __restrict__ A,
    const u16* __restrict__ Wd0, const u16* __restrict__ Wd1,
    u16* __restrict__ Cd0, u16* __restrict__ Cd1,
    int lda, int ldw, int ldc, int K)
{
    __shared__ u16 lds[65536];                 // 128 KiB
    const int t    = threadIdx.x;
    const int lane = t & 63;
    const int w    = t >> 6;
    const int wr   = w >> 2;                   // 0..1
    const int wc   = w & 3;                    // 0..3
    const int fm   = lane & 15;
    const int q    = lane >> 4;
    const int dir  = blockIdx.z;
    const u16* W   = dir ? Wd1 : Wd0;
    u16* C         = dir ? Cd1 : Cd0;
    const int m0   = blockIdx.y * 256;
    const int n0   = blockIdx.x * 256;
    const int T    = K >> 6;                   // K-tiles (16 for K=1024)

    // ds_read u16 offsets within a 128x64 half (slot*8 u16)
    int offA[4][2], offW[2][2];
    #pragma unroll
    for (int mi = 0; mi < 4; mi++)
        #pragma unroll
        for (int kk = 0; kk < 2; kk++) {
            int r = wr * 64 + mi * 16 + fm;
            int j = kk * 4 + q;
            offA[mi][kk] = (r * 8 + ((j + r) & 7)) * 8;
        }
    #pragma unroll
    for (int ni = 0; ni < 2; ni++)
        #pragma unroll
        for (int kk = 0; kk < 2; kk++) {
            int r = wc * 32 + ni * 16 + fm;
            int j = kk * 4 + q;
            offW[ni][kk] = (r * 8 + ((j + r) & 7)) * 8;
        }

    // staging decomposition: slot = p*512 + t; r = slot>>3; j = ((slot&7)-r)&7
    int sr[2], sj[2];
    #pragma unroll
    for (int p = 0; p < 2; p++) {
        int slot = p * 512 + t;
        sr[p] = slot >> 3;
        sj[p] = ((slot & 7) - sr[p]) & 7;
    }
    const int ldsWaveBase = (t & ~63) * 8;     // u16; p adds 4096

#define STAGE(G, ld, row0, kcol, dstBase)                                    \
    { _Pragma("unroll")                                                      \
      for (int p = 0; p < 2; p++) {                                          \
          const u16* src_ = (G) + (size_t)((row0) + sr[p]) * (ld)            \
                          + (kcol) + sj[p] * 8;                              \
          async16(src_, &lds[(dstBase) + p * 4096 + ldsWaveBase]);           \
      } }

    f32x4 acc[2][2][4][2] = {};
    bf16x8 af[4][2], wf[2][2];

#define DSREAD_A(mh, cur)                                                    \
    { _Pragma("unroll")                                                      \
      for (int mi = 0; mi < 4; mi++)                                         \
          _Pragma("unroll")                                                  \
          for (int kk = 0; kk < 2; kk++)                                     \
              af[mi][kk] = *(const bf16x8*)&lds[(cur) + (mh) * 8192          \
                                                + offA[mi][kk]]; }
#define DSREAD_W(nh, cur)                                                    \
    { _Pragma("unroll")                                                      \
      for (int ni = 0; ni < 2; ni++)                                         \
          _Pragma("unroll")                                                  \
          for (int kk = 0; kk < 2; kk++)                                     \
              wf[ni][kk] = *(const bf16x8*)&lds[(cur) + 16384 + (nh) * 8192  \
                                                + offW[ni][kk]]; }
#define MFMA16(mh, nh)                                                       \
    { __builtin_amdgcn_s_setprio(1);                                         \
      _Pragma("unroll")                                                      \
      for (int mi = 0; mi < 4; mi++)                                         \
          _Pragma("unroll")                                                  \
          for (int ni = 0; ni < 2; ni++)                                     \
              _Pragma("unroll")                                              \
              for (int kk = 0; kk < 2; kk++)                                 \
                  acc[mh][nh][mi][ni] =                                      \
                      __builtin_amdgcn_mfma_f32_16x16x32_bf16(               \
                          af[mi][kk], wf[ni][kk], acc[mh][nh][mi][ni],       \
                          0, 0, 0);                                          \
      __builtin_amdgcn_s_setprio(0); }

#define WAITVM(n) asm volatile("s_waitcnt vmcnt(" #n ")" ::: "memory")
#define BAR() __builtin_amdgcn_s_barrier()

    // prologue: tile 0 -> buf0; issue order Ah0, Wh0, Wh1, Ah1
    STAGE(A, lda, m0,       0, 0);
    STAGE(W, ldw, n0,       0, 16384);
    STAGE(W, ldw, n0 + 128, 0, 16384 + 8192);
    STAGE(A, lda, m0 + 128, 0, 8192);
    WAITVM(4);                    // Ah0,Wh0 landed; Wh1,Ah1 in flight
    BAR();

    for (int tt = 0; tt < T - 1; ++tt) {
        const int cur = (tt & 1) * 32768;
        const int nxt = 32768 - cur;
        const int kn  = (tt + 1) << 6;
        // phase 0: quadrant (0,0); stage Ah0(t+1); guard Wh1(t) for p1
        DSREAD_A(0, cur); DSREAD_W(0, cur);
        STAGE(A, lda, m0, kn, nxt);
        WAITVM(4);
        BAR();
        MFMA16(0, 0);
        BAR();
        // phase 1: quadrant (0,1) (A-frags reused); stage Wh0(t+1); guard Ah1(t)
        DSREAD_W(1, cur);
        STAGE(W, ldw, n0, kn, nxt + 16384);
        WAITVM(4);
        BAR();
        MFMA16(0, 1);
        BAR();
        // phase 2: quadrant (1,1) (W-frags reused); stage Wh1(t+1); no wait
        DSREAD_A(1, cur);
        STAGE(W, ldw, n0 + 128, kn, nxt + 16384 + 8192);
        BAR();
        MFMA16(1, 1);
        BAR();
        // phase 3: quadrant (1,0); stage Ah1(t+1); guard Ah0,Wh0(t+1) for next
        DSREAD_W(0, cur);
        STAGE(A, lda, m0 + 128, kn, nxt + 8192);
        WAITVM(4);
        BAR();
        MFMA16(1, 0);
        BAR();
    }
    // tail tile T-1 (no staging; drain allowed)
    {
        const int cur = ((T - 1) & 1) * 32768;
        DSREAD_A(0, cur); DSREAD_W(0, cur);
        WAITVM(2);                 // Wh1 ready for p1
        BAR();
        MFMA16(0, 0);
        BAR();
        DSREAD_W(1, cur);
        WAITVM(0);                 // Ah1 ready for p2
        BAR();
        MFMA16(0, 1);
        BAR();
        DSREAD_A(1, cur);
        BAR();
        MFMA16(1, 1);
        BAR();
        DSREAD_W(0, cur);
        MFMA16(1, 0);
    }
#undef STAGE
#undef DSREAD_A
#undef DSREAD_W
#undef MFMA16
#undef WAITVM
#undef BAR

    // epilogue: C/D layout col=lane&15, row=(lane>>4)*4+reg; bf16 store
    #pragma unroll
    for (int mh = 0; mh < 2; mh++)
        #pragma unroll
        for (int mi = 0; mi < 4; mi++)
            #pragma unroll
            for (int rr = 0; rr < 4; rr++) {
                int gm = m0 + mh * 128 + wr * 64 + mi * 16 + q * 4 + rr;
                int om = gm;
                if (dir == 1) {                      // flip within batch SEQ
                    om = (gm & ~(SEQ - 1)) | ((SEQ - 1) - (gm & (SEQ - 1)));
                }
                u16* crow = C + (size_t)om * ldc;
                #pragma unroll
                for (int nh = 0; nh < 2; nh++)
                    #pragma unroll
                    for (int ni = 0; ni < 2; ni++) {
                        int gn = n0 + nh * 128 + wc * 32 + ni * 16 + fm;
                        crow[gn] = f2b(acc[mh][nh][mi][ni][rr]);
                    }
            }
}

// ---------------- dual-direction MFMA GEMM (steps 3,4,6,7) -----------------
// 2-PHASE double-buffered LDS (R9-proven). SWZ: bijective XCD remap.
template <typename TA, typename TC, int ACT, bool DUAL, bool FLIP1, int NSPLIT,
          int BN, bool SWZ>
__global__ __launch_bounds__(256) void mfma_gemm(
    const TA* __restrict__ A0, const TA* __restrict__ A1, int lda,
    const u16* __restrict__ W0, const u16* __restrict__ W1, int ldw,
    const float* __restrict__ bias0, const float* __restrict__ bias1,
    TC* __restrict__ C0, TC* __restrict__ C1, int ldc,
    int M, int N, int K)
{
    constexpr int NF = BN / 32;          // n-fragments per wave (2 or 4)
    __shared__ u16 As[2][128 * 32];
    __shared__ u16 Ws[2][BN * 32];

    int bx = blockIdx.x, by = blockIdx.y, bz = blockIdx.z;
    if (SWZ) {
        const int gx = gridDim.x, gy = gridDim.y;
        const int nwg = gx * gy * gridDim.z;
        int flat = (blockIdx.z * gy + blockIdx.y) * gx + blockIdx.x;
        flat = xcd_swz(flat, nwg);
        bx = flat % gx;
        int rest = flat / gx;
        by = rest % gy;
        bz = rest / gy;
    }

    const int z = bz;
    const int dir = DUAL ? (z / NSPLIT) : 0;
    const int split = z % NSPLIT;
    const TA* A = dir ? A1 : A0;
    const u16* W = dir ? W1 : W0;
    const float* bias = dir ? bias1 : bias0;
    TC* C = dir ? C1 : C0;
    if (NSPLIT > 1) C += (size_t)split * M * ldc;
    const int kseg = K / NSPLIT;
    const int kbeg = split * kseg;
    const int kiters = kseg / 32;

    const int t = threadIdx.x;
    const int wave = t >> 6;
    const int lane = t & 63;
    const int wm = (wave & 1) * 64;
    const int wn = (wave >> 1) * (BN / 2);
    const int fm = lane & 15;
    const int q  = lane >> 4;
    const int m0 = by * 128;
    const int n0 = bx * BN;

    auto stage_tile = [&](int k0, int b) {
        if constexpr (__is_same(TA, u16)) {
            #pragma unroll
            for (int p = 0; p < 2; p++) {
                int i = p * 256 + wave * 64 + lane;
                int r = i >> 2;
                int j = ((i & 3) - (r >> 1)) & 3;
                async16(A + (size_t)(m0 + r) * lda + k0 + j * 8,
                        &As[b][(size_t)(p * 256 + wave * 64) * 8]);
            }
        } else {
            #pragma unroll
            for (int p = 0; p < 2; p++) {
                int i = p * 256 + t;
                int r = i >> 2;
                int j = ((i & 3) - (r >> 1)) & 3;
                stage8f(A + (size_t)(m0 + r) * lda + k0 + j * 8,
                        &As[b][(size_t)i * 8]);
            }
        }
        #pragma unroll
        for (int p = 0; p < BN / 64; p++) {
            int i = p * 256 + wave * 64 + lane;
            int r = i >> 2;
            int j = ((i & 3) - (r >> 1)) & 3;
            int gr = n0 + r;
            if (gr >= N) gr = N - 1;   // clamp (junk discarded at store)
            async16(W + (size_t)gr * ldw + k0 + j * 8,
                    &Ws[b][(size_t)(p * 256 + wave * 64) * 8]);
        }
    };

    f32x4 acc[4][NF] = {};

    stage_tile(kbeg, 0);
    __syncthreads();

    for (int ii = 0; ii < kiters; ii++) {
        const int cur = ii & 1;
        if (ii + 1 < kiters)
            stage_tile(kbeg + (ii + 1) * 32, cur ^ 1);   // prefetch next tile

        bf16x8 af[4], wf[NF];
        #pragma unroll
        for (int mi = 0; mi < 4; mi++)
            af[mi] = *(const bf16x8*)
                &As[cur][(size_t)lds_slot(wm + mi * 16 + fm, q) * 8];
        #pragma unroll
        for (int ni = 0; ni < NF; ni++)
            wf[ni] = *(const bf16x8*)
                &Ws[cur][(size_t)lds_slot(wn + ni * 16 + fm, q) * 8];
        #pragma unroll
        for (int mi = 0; mi < 4; mi++)
            #pragma unroll
            for (int ni = 0; ni < NF; ni++)
                acc[mi][ni] = __builtin_amdgcn_mfma_f32_16x16x32_bf16(
                    af[mi], wf[ni], acc[mi][ni], 0, 0, 0);

        __syncthreads();   // vmcnt(0)+lgkmcnt(0)+barrier: next buf ready,
                           // cur buf fully consumed by all waves
    }

    // C/D layout: col = lane&15, row = (lane>>4)*4 + reg
    const int rb = q * 4;
    const int cc = fm;
    #pragma unroll
    for (int mi = 0; mi < 4; mi++) {
        #pragma unroll
        for (int r = 0; r < 4; r++) {
            int gm = m0 + wm + mi * 16 + rb + r;
            int om = gm;
            if (FLIP1 && dir == 1) {
                int bb = gm / SEQ, l = gm % SEQ;
                om = bb * SEQ + (SEQ - 1 - l);
            }
            #pragma unroll
            for (int ni = 0; ni < NF; ni++) {
                int gn = n0 + wn + ni * 16 + cc;
                if (gn < N) {
                    float v = acc[mi][ni][r];
                    if (ACT == 1) v = softplus_fast(v + bias[gn]);
                    stf(C, (size_t)om * ldc + gn, v);
                }
            }
        }
    }
}

// ---- split-K combines ----
__global__ __launch_bounds__(256) void combine_dbl_kernel(
    const float* __restrict__ par, float* __restrict__ dbl)
{
    int i4 = blockIdx.x * 256 + threadIdx.x;   // [0, 2*MM*NDBL/4)
    const int per = (MM * NDBL) / 4;           // 49152
    int dir = (i4 >= per) ? 1 : 0;
    int j4 = i4 - dir * per;
    const float* p = par + (size_t)dir * 4 * MM * NDBL;
    f32x4 s = {0.f, 0.f, 0.f, 0.f};
    #pragma unroll
    for (int k = 0; k < 4; k++)
        s += *(const f32x4*)&p[(size_t)k * MM * NDBL + (size_t)j4 * 4];
    *(f32x4*)&dbl[(size_t)dir * MM * NDBL + (size_t)j4 * 4] = s;
}

__global__ __launch_bounds__(256) void combine_cat_kernel(
    const float* __restrict__ par, u16* __restrict__ cat)
{
    int i4 = blockIdx.x * 256 + threadIdx.x;   // [0, 2*MM*DM/4)
    const int per = (MM * DM) / 4;             // 524288
    int dir = (i4 >= per) ? 1 : 0;
    int j4 = i4 - dir * per;
    const float* p0 = par + (size_t)dir * 2 * MM * DM;
    const float* p1 = p0 + (size_t)MM * DM;
    f32x4 a = *(const f32x4*)&p0[(size_t)j4 * 4];
    f32x4 b = *(const f32x4*)&p1[(size_t)j4 * 4];
    int m = j4 >> 8;           // DM/4 = 256 float4 per row
    int n4 = j4 & 255;
    ushort4 o;
    o.x = f2b(a[0] + b[0]); o.y = f2b(a[1] + b[1]);
    o.z = f2b(a[2] + b[2]); o.w = f2b(a[3] + b[3]);
    *(ushort4*)&cat[(size_t)m * 2 * DM + dir * DM + n4 * 4] = o;
}

__global__ __launch_bounds__(256) void combine_out_kernel(
    const float* __restrict__ p0, float* __restrict__ out)
{
    int i4 = blockIdx.x * 256 + threadIdx.x;   // [0, MM*DM/4)
    const float* p1 = p0 + (size_t)MM * DM;
    f32x4 a = *(const f32x4*)&p0[(size_t)i4 * 4];
    f32x4 b = *(const f32x4*)&p1[(size_t)i4 * 4];
    *(f32x4*)&out[(size_t)i4 * 4] = a + b;
}

// ---- conv + silu, both dirs, 4 channels/thread; xz is bf16 ----
__global__ __launch_bounds__(256) void conv_silu_kernel(
    const u16* __restrict__ xz,
    const float* __restrict__ cw0, const float* __restrict__ cw1,
    const float* __restrict__ cb0, const float* __restrict__ cb1,
    u16* __restrict__ xcb)
{
    int i4 = blockIdx.x * 256 + threadIdx.x;    // [0, 2*MM*DI/4)
    const int per = MM * DI / 4;
    int dir = (i4 >= per) ? 1 : 0;
    int rem = i4 - dir * per;
    int e4 = rem & (DI / 4 - 1);
    int bl = rem / (DI / 4);
    int l = bl & (SEQ - 1);
    int e = e4 * 4;
    const u16* xz_d = xz + (size_t)dir * MM * 2 * DI;
    const float* cw = dir ? cw1 : cw0;
    const float* cb = dir ? cb1 : cb0;
    f32x4 cwv[4];
    #pragma unroll
    for (int i = 0; i < 4; i++) cwv[i] = *(const f32x4*)&cw[(e + i) * DC];
    f32x4 acc = *(const f32x4*)&cb[e];
    #pragma unroll
    for (int k = 0; k < DC; k++) {
        int ll = l + k - (DC - 1);
        if (ll >= 0) {
            ushort4 xv = *(const ushort4*)&xz_d[(size_t)(bl - l + ll) * (2 * DI) + e];
            acc[0] += cwv[0][k] * b2f(xv.x);
            acc[1] += cwv[1][k] * b2f(xv.y);
            acc[2] += cwv[2][k] * b2f(xv.z);
            acc[3] += cwv[3][k] * b2f(xv.w);
        }
    }
    ushort4 o;
    #pragma unroll
    for (int i = 0; i < 4; i++) {
        float s = silu_fast(acc[i]);
        ((u16*)&o)[i] = f2b(s);
    }
    ((ushort4*)xcb)[(size_t)dir * per + rem] = o;
}

// ---- Chunked scan, both dirs, n-in-registers; xc is bf16 ----
// P-ELIMINATION (R6) + POWER FAST PATH (R7) + LDS INPUT STAGING (R9).
// grid (NC, DI/256, 2*BSZ); z: dir = z>>1, b = z&1.
__global__ __launch_bounds__(256) void scan_pass1(
    const float* __restrict__ dbl,
    const u16*  __restrict__ xc,
    const u16*  __restrict__ delta,
    const float* __restrict__ Alog0, const float* __restrict__ Alog1,
    float* __restrict__ Qout, float* __restrict__ Dout)
{
    __shared__ float sB[LC][16];
    __shared__ u16 sD[LC * 256];     // delta tile, 16 KB
    __shared__ u16 sX[LC * 256];     // xc tile,    16 KB
    const int t = threadIdx.x;
    const int c = blockIdx.x;
    const int dir = blockIdx.z >> 1;
    const int b = blockIdx.z & 1;
    const int ey = blockIdx.y;
    const int e = ey * 256 + t;
    const int row0 = b * SEQ + c * LC;
    const float* dbl_d = dbl + (size_t)dir * MM * NDBL;
    const u16* xc_d = xc + (size_t)dir * MM * DI;
    const u16* delta_d = delta + (size_t)dir * MM * DI;
    const float* A_log = dir ? Alog1 : Alog0;
    float* Q_d = Qout + (size_t)dir * BSZ * NC * DI * DS;
    float* D_d = Dout + (size_t)dir * BSZ * NC * DI;

    stage_tile256(delta_d, row0, DI, ey * 256, sD, t);
    stage_tile256(xc_d,    row0, DI, ey * 256, sX, t);

    if (t < LC * 4) {
        int row = t >> 2, col = (t & 3) * 4;
        *(f32x4*)&sB[row][col] =
            *(const f32x4*)&dbl_d[(size_t)(row0 + row) * NDBL + DR + col];
    }

    f32x4 Aen[4], Q[4];
    #pragma unroll
    for (int g = 0; g < 4; g++) {
        f32x4 a = *(const f32x4*)&A_log[(size_t)e * DS + g * 4];
        #pragma unroll
        for (int j = 0; j < 4; j++) Aen[g][j] = -fexp(a[j]);
        Q[g] = f32x4{0.f, 0.f, 0.f, 0.f};
    }
    const float a0 = Aen[0][0];
    bool pw = true;
    #pragma unroll
    for (int g = 0; g < 4; g++)
        #pragma unroll
        for (int j = 0; j < 4; j++)
            pw = pw && (fabsf(Aen[g][j] - (float)(g * 4 + j + 1) * a0)
                        <= 1e-4f * fabsf(Aen[g][j]));
    __syncthreads();   // staging (vmcnt) + sB visible to all

    float dsum = 0.f;
    if (pw) {
        for (int i = 0; i < LC; i++) {
            float dv = b2f(sD[i * 256 + t]);
            float xv = b2f(sX[i * 256 + t]);
            float du = dv * xv;
            dsum += dv;
            float e1 = fexp(dv * a0);
            float e2 = e1 * e1, e3 = e2 * e1, e4 = e2 * e2;
            float e8 = e4 * e4, e12 = e8 * e4;
            float lo[4] = {e1, e2, e3, e4};
            float Eg[4] = {1.f, e4, e8, e12};
            #pragma unroll
            for (int g = 0; g < 4; g++) {
                f32x4 Bv = *(const f32x4*)&sB[i][g * 4];
                #pragma unroll
                for (int j = 0; j < 4; j++) {
                    float dA = (g == 0) ? lo[j] : Eg[g] * lo[j];
                    Q[g][j] = dA * Q[g][j] + du * Bv[j];
                }
            }
        }
    } else {
        for (int i = 0; i < LC; i++) {
            float dv = b2f(sD[i * 256 + t]);
            float xv = b2f(sX[i * 256 + t]);
            float du = dv * xv;
            dsum += dv;
            #pragma unroll
            for (int g = 0; g < 4; g++) {
                f32x4 Bv = *(const f32x4*)&sB[i][g * 4];
                #pragma unroll
                for (int j = 0; j < 4; j++) {
                    float dA = fexp(dv * Aen[g][j]);
                    Q[g][j] = dA * Q[g][j] + du * Bv[j];
                }
            }
        }
    }
    size_t base = ((size_t)(b * NC + c) * DI + e) * DS;
    #pragma unroll
    for (int g = 0; g < 4; g++)
        *(f32x4*)&Q_d[base + g * 4] = Q[g];
    D_d[(size_t)(b * NC + c) * DI + e] = dsum;
}

// pass2: stitch chunks. h_{c+1} = exp(Aen_j * Dsum[c]) * h_c + Q[c].
__global__ __launch_bounds__(256) void scan_pass2(
    const float* __restrict__ Q, const float* __restrict__ Dsum,
    const float* __restrict__ Alog0, const float* __restrict__ Alog1,
    float* __restrict__ H0)
{
    const int gid = blockIdx.x * 256 + threadIdx.x;  // [0, 2*BSZ*DI*DS)
    const int dir = gid >> 16;
    const int loc = gid & 65535;
    const int b = loc >> 15;
    const int en = loc & (DI * DS - 1);              // e*DS + j
    const int e = en >> 4;
    const float* A_log = dir ? Alog1 : Alog0;
    const float aen = -fexp(A_log[en]);
    size_t doff = (size_t)dir * BSZ * NC * DI * DS;
    size_t doffD = (size_t)dir * BSZ * NC * DI;
    float h = 0.f;
    for (int c = 0; c < NC; c++) {
        size_t idx = doff + ((size_t)(b * NC + c) * DI * DS) + en;
        H0[idx] = h;
        float Dc = Dsum[doffD + (size_t)(b * NC + c) * DI + e];
        h = fexp(Dc * aen) * h + Q[idx];
    }
}

// pass3: replay chunk; writes gated y IN-PLACE over delta; z is bf16.
// Inputs (delta, xc, z) staged to LDS up front (R9).
__global__ __launch_bounds__(256) void scan_pass3(
    const float* __restrict__ dbl,
    const u16*  __restrict__ xc,
    const u16*  __restrict__ xz,
    u16* delta_y,
    const float* __restrict__ Alog0, const float* __restrict__ Alog1,
    const float* __restrict__ Dp0, const float* __restrict__ Dp1,
    const float* __restrict__ H0)
{
    __shared__ float sBC[LC][32];
    __shared__ u16 sD[LC * 256];     // delta tile, 16 KB
    __shared__ u16 sX[LC * 256];     // xc tile,    16 KB
    __shared__ u16 sZ[LC * 256];     // z tile,     16 KB
    const int t = threadIdx.x;
    const int c = blockIdx.x;
    const int dir = blockIdx.z >> 1;
    const int b = blockIdx.z & 1;
    const int ey = blockIdx.y;
    const int e = ey * 256 + t;
    const int row0 = b * SEQ + c * LC;
    const float* dbl_d = dbl + (size_t)dir * MM * NDBL;
    const u16* xc_d = xc + (size_t)dir * MM * DI;
    const u16* xz_d = xz + (size_t)dir * MM * 2 * DI;
    u16* dy_d = delta_y + (size_t)dir * MM * DI;
    const float* A_log = dir ? Alog1 : Alog0;
    const float* Dp = dir ? Dp1 : Dp0;
    const float* H0_d = H0 + (size_t)dir * BSZ * NC * DI * DS;

    stage_tile256(dy_d, row0, DI, ey * 256, sD, t);
    stage_tile256(xc_d, row0, DI, ey * 256, sX, t);
    stage_tile256(xz_d, row0, 2 * DI, DI + ey * 256, sZ, t);  // z half

    {
        int row = t >> 3, col = (t & 7) * 4;
        *(f32x4*)&sBC[row][col] =
            *(const f32x4*)&dbl_d[(size_t)(row0 + row) * NDBL + DR + col];
    }

    f32x4 Aen[4], h[4];
    size_t base = ((size_t)(b * NC + c) * DI + e) * DS;
    #pragma unroll
    for (int g = 0; g < 4; g++) {
        f32x4 a = *(const f32x4*)&A_log[(size_t)e * DS + g * 4];
        #pragma unroll
        for (int j = 0; j < 4; j++) Aen[g][j] = -fexp(a[j]);
        h[g] = *(const f32x4*)&H0_d[base + g * 4];
    }
    const float Dv = Dp[e];
    const float a0 = Aen[0][0];
    bool pw = true;
    #pragma unroll
    for (int g = 0; g < 4; g++)
        #pragma unroll
        for (int j = 0; j < 4; j++)
            pw = pw && (fabsf(Aen[g][j] - (float)(g * 4 + j + 1) * a0)
                        <= 1e-4f * fabsf(Aen[g][j]));
    __syncthreads();   // staging (vmcnt) + sBC visible to all

    if (pw) {
        for (int i = 0; i < LC; i++) {
            float dv = b2f(sD[i * 256 + t]);
            float xv = b2f(sX[i * 256 + t]);
            float zv = b2f(sZ[i * 256 + t]);
            float du = dv * xv;
            float e1 = fexp(dv * a0);
            float e2 = e1 * e1, e3 = e2 * e1, e4 = e2 * e2;
            float e8 = e4 * e4, e12 = e8 * e4;
            float lo[4] = {e1, e2, e3, e4};
            float Eg[4] = {1.f, e4, e8, e12};
            f32x4 pv = {0.f, 0.f, 0.f, 0.f};
            #pragma unroll
            for (int g = 0; g < 4; g++) {
                f32x4 Bv = *(const f32x4*)&sBC[i][g * 4];
                f32x4 Cv = *(const f32x4*)&sBC[i][16 + g * 4];
                #pragma unroll
                for (int j = 0; j < 4; j++) {
                    float dA = (g == 0) ? lo[j] : Eg[g] * lo[j];
                    h[g][j] = dA * h[g][j] + du * Bv[j];
                    pv[j] += h[g][j] * Cv[j];
                }
            }
            float p = pv[0] + pv[1] + pv[2] + pv[3];
            float y = (p + xv * Dv) * silu_fast(zv);
            dy_d[(size_t)(row0 + i) * DI + e] = f2b(y);
        }
    } else {
        for (int i = 0; i < LC; i++) {
            float dv = b2f(sD[i * 256 + t]);
            float xv = b2f(sX[i * 256 + t]);
            float zv = b2f(sZ[i * 256 + t]);
            float du = dv * xv;
            f32x4 pv = {0.f, 0.f, 0.f, 0.f};
            #pragma unroll
            for (int g = 0; g < 4; g++) {
                f32x4 Bv = *(const f32x4*)&sBC[i][g * 4];
                f32x4 Cv = *(const f32x4*)&sBC[i][16 + g * 4];
                #pragma unroll
                for (int j = 0; j < 4; j++) {
                    float dA = fexp(dv * Aen[g][j]);
                    h[g][j] = dA * h[g][j] + du * Bv[j];
                    pv[j] += h[g][j] * Cv[j];
                }
            }
            float p = pv[0] + pv[1] + pv[2] + pv[3];
            float y = (p + xv * Dv) * silu_fast(zv);
            dy_d[(size_t)(row0 + i) * DI + e] = f2b(y);
        }
    }
}

extern "C" void kernel_launch(void* const* d_in, const int* in_sizes, int n_in,
                              void* d_out, int out_size, void* d_ws, size_t ws_size,
                              hipStream_t stream)
{
    const float* x = (const float*)d_in[0];
    const float* in_p[2]  = {(const float*)d_in[1],  (const float*)d_in[10]};
    const float* conv_w[2]= {(const float*)d_in[2],  (const float*)d_in[11]};
    const float* conv_b[2]= {(const float*)d_in[3],  (const float*)d_in[12]};
    const float* x_p[2]   = {(const float*)d_in[4],  (const float*)d_in[13]};
    const float* dt_w[2]  = {(const float*)d_in[5],  (const float*)d_in[14]};
    const float* dt_b[2]  = {(const float*)d_in[6],  (const float*)d_in[15]};
    const float* A_log[2] = {(const float*)d_in[7],  (const float*)d_in[16]};
    const float* Dp[2]    = {(const float*)d_in[8],  (const float*)d_in[17]};
    const float* out_p[2] = {(const float*)d_in[9],  (const float*)d_in[18]};
    const float* merge_w  = (const float*)d_in[19];
    float* out = (float*)d_out;

    // ---- workspace layout (element units) ----
    float* ws = (float*)d_ws;
    float* ws_dbl = ws;                                    // 2 * MM*NDBL f
    float* ws_Q   = ws_dbl + (size_t)2 * MM * NDBL;        // 2 * BSZ*NC*DI*DS f
    float* ws_D   = ws_Q   + (size_t)2 * BSZ * NC * DI * DS; // 2*BSZ*NC*DI f
    float* ws_H0  = ws_D   + (size_t)2 * BSZ * NC * DI;
    u16* ws_xz    = (u16*)(ws_H0 + (size_t)2 * BSZ * NC * DI * DS); // 2*MM*2DI u16
    u16* ws_delta = ws_xz    + (size_t)2 * MM * 2 * DI;    // 2*MM*DI u16
    u16* ws_xcb   = ws_delta + (size_t)2 * MM * DI;        // 2*MM*DI u16
    u16* ws_cat   = ws_xcb   + (size_t)2 * MM * DI;        // MM*2DM u16
    u16* ws_xbf   = ws_cat   + (size_t)MM * 2 * DM;        // MM*DM u16
    u16* wbf_mw   = ws_xbf   + (size_t)MM * DM;            // DM*2DM u16
    u16* wbf0     = wbf_mw   + (size_t)DM * 2 * DM;        // WBF_SZ u16
    u16* wbf1     = wbf0     + WBF_SZ;                     // WBF_SZ u16
    // split-K partials alias Q (dead after pass2):
    // step-3 needs 2*4*MM*NDBL = 1.6M f; step-6 needs 2*2*MM*DM = 8.39M f;
    // step-7 needs 2*MM*DM = 4.19M f; Q region = 8.39M f -> fits.
    float* ws_par = ws_Q;

    // 0) one-shot convert: x, merge_w, all weights (both dirs)
    cvt_all_kernel<<<(N4_TOTAL + 255) / 256, 256, 0, stream>>>(
        x, merge_w, in_p[0], x_p[0], dt_w[0], out_p[0],
        in_p[1], x_p[1], dt_w[1], out_p[1],
        ws_xbf, wbf_mw,
        wbf0, wbf0 + O_XP, wbf0 + O_DT, wbf0 + O_OUT,
        wbf1, wbf1 + O_XP, wbf1 + O_DT, wbf1 + O_OUT);

    // 1) xz = x @ in_proj^T (both dirs; dir1 rows flipped) — 256x256 8-phase,
    //    bf16 out (R5 lesson: this structure wins at this shape).
    gemm256_dual<<<dim3(16, 8, 2), 512, 0, stream>>>(
        ws_xbf, wbf0, wbf1,
        ws_xz, ws_xz + (size_t)MM * 2 * DI,
        DM, DM, 2 * DI, DM);

    // 2) conv + silu (both dirs, 4-wide, bf16 in/out)
    conv_silu_kernel<<<(2 * MM * DI / 4) / 256, 256, 0, stream>>>(
        ws_xz, conv_w[0], conv_w[1], conv_b[0], conv_b[1], ws_xcb);

    // 3) dbl = xc @ x_proj^T  (N=96, split-K4, both dirs, XCD-swizzled)
    mfma_gemm<u16, float, 0, true, false, 4, 64, true>
        <<<dim3(2, 16, 8), 256, 0, stream>>>(
        ws_xcb, ws_xcb + (size_t)MM * DI, DI,
        wbf0 + O_XP, wbf1 + O_XP, DI, nullptr, nullptr,
        ws_par, ws_par + (size_t)4 * MM * NDBL, NDBL, MM, NDBL, DI);
    combine_dbl_kernel<<<(2 * MM * NDBL / 4) / 256, 256, 0, stream>>>(ws_par, ws_dbl);

    // 4) delta = softplus(dt @ dt_w^T + dt_b) -> bf16 (K=64, fp32 A, both dirs)
    mfma_gemm<float, u16, 1, true, false, 1, 64, true>
        <<<dim3(32, 16, 2), 256, 0, stream>>>(
        ws_dbl, ws_dbl + (size_t)MM * NDBL, NDBL,
        wbf0 + O_DT, wbf1 + O_DT, DR, dt_b[0], dt_b[1],
        ws_delta, ws_delta + (size_t)MM * DI, DI, MM, DI, DR);

    // 5) chunked scan (both dirs); P eliminated via chunk delta-sum;
    //    power fast path for dA; LDS-staged inputs; pass3 writes y over delta
    {
        dim3 grid(NC, DI / 256, 2 * BSZ);
        scan_pass1<<<grid, 256, 0, stream>>>(ws_dbl, ws_xcb, ws_delta,
                                             A_log[0], A_log[1], ws_Q, ws_D);
        scan_pass2<<<(2 * BSZ * DI * DS) / 256, 256, 0, stream>>>(
            ws_Q, ws_D, A_log[0], A_log[1], ws_H0);
        scan_pass3<<<grid, 256, 0, stream>>>(ws_dbl, ws_xcb, ws_xz, ws_delta,
                                             A_log[0], A_log[1], Dp[0], Dp[1], ws_H0);
    }

    // 6) cat = y @ out_proj^T — K=2048 is the deepest loop: split-K2 ->
    //    1024 blocks (4/CU), 32 iters each; fp32 partials + combine_cat.
    //    (R13: the single isolated change vs R12.)
    mfma_gemm<u16, float, 0, true, true, 2, 64, true>
        <<<dim3(16, 16, 4), 256, 0, stream>>>(
        ws_delta, ws_delta + (size_t)MM * DI, DI,
        wbf0 + O_OUT, wbf1 + O_OUT, DI, nullptr, nullptr,
        ws_par, ws_par + (size_t)2 * MM * DM, DM, MM, DM, DI);
    combine_cat_kernel<<<(2 * MM * DM / 4) / 256, 256, 0, stream>>>(ws_par, ws_cat);

    // 7) out = cat @ merge_w^T — BN=64, split-K2 (512 blocks), XCD-swizzled
    mfma_gemm<u16, float, 0, false, false, 2, 64, true>
        <<<dim3(16, 16, 2), 256, 0, stream>>>(
        ws_cat, ws_cat, 2 * DM, wbf_mw, wbf_mw, 2 * DM, nullptr, nullptr,
        ws_par, ws_par, DM, MM, DM, 2 * DM);
    combine_out_kernel<<<(MM * DM / 4) / 256, 256, 0, stream>>>(ws_par, out);
}

// Round 14
// 325.683 us; speedup vs baseline: 1.0242x; 1.0242x over previous
//
#include <hip/hip_runtime.h>
#include <math.h>

#define BSZ 2
#define SEQ 1024
#define DM  1024          // d_model
#define DI  2048          // d_inner
#define DS  16            // d_state
#define DC  4             // d_conv
#define DR  64            // dt_rank
#define NDBL 96           // DR + 2*DS
#define NC  32            // scan chunks
#define LC  32            // SEQ / NC
#define MM  (BSZ * SEQ)   // 2048 rows

typedef unsigned short u16;
typedef __bf16 bf16x8 __attribute__((ext_vector_type(8)));
typedef float  f32x4  __attribute__((ext_vector_type(4)));

// ---- segment sizes (float4 units) and weight-block offsets (u16 units) ----
constexpr int N4_X   = MM * DM / 4;          //   524,288
constexpr int N4_MW  = DM * 2 * DM / 4;      //   524,288
constexpr int N4_IN  = 2 * DI * DM / 4;      // 1,048,576
constexpr int N4_XP  = NDBL * DI / 4;        //    49,152
constexpr int N4_DT  = DI * DR / 4;          //    32,768
constexpr int N4_OUT = DM * DI / 4;          //   524,288
constexpr int N4_TOTAL = N4_X + N4_MW + 2 * (N4_IN + N4_XP + N4_DT + N4_OUT);
constexpr size_t O_XP  = (size_t)2 * DI * DM;            // 4,194,304
constexpr size_t O_DT  = O_XP + (size_t)NDBL * DI;       // 4,390,912
constexpr size_t O_OUT = O_DT + (size_t)DI * DR;         // 4,521,984
constexpr size_t WBF_SZ = O_OUT + (size_t)DM * DI;       // 6,619,136 u16 per dir

__device__ __forceinline__ u16 f2b(float f) {
    unsigned int u = __float_as_uint(f);
    unsigned int r = (u + 0x7fffu + ((u >> 16) & 1u)) >> 16;
    return (u16)r;
}
__device__ __forceinline__ float b2f(u16 h) {
    return __uint_as_float(((unsigned int)h) << 16);
}

__device__ __forceinline__ void stf(float* p, size_t i, float v) { p[i] = v; }
__device__ __forceinline__ void stf(u16* p, size_t i, float v)   { p[i] = f2b(v); }

// ---- fast transcendentals ----
__device__ __forceinline__ float fexp(float x)  { return __expf(x); }
__device__ __forceinline__ float frcp(float x)  { return __builtin_amdgcn_rcpf(x); }
__device__ __forceinline__ float silu_fast(float x) {
    return x * frcp(1.f + fexp(-x));
}
__device__ __forceinline__ float softplus_fast(float x) {
    return (x > 15.f) ? x : __logf(1.f + fexp(x));
}

// ---- async global->LDS, 16B/lane; dest = wave-uniform base + lane*16 ----
__device__ __forceinline__ void async16(const u16* g, u16* l) {
    __builtin_amdgcn_global_load_lds(
        (const __attribute__((address_space(1))) void*)g,
        (__attribute__((address_space(3))) void*)l, 16, 0, 0);
}

// XOR-swizzle: 16B-slot for (row, 8-elem chunk j) — 2-way bank aliasing only.
__device__ __forceinline__ int lds_slot(int row, int j) {
    return row * 4 + ((j + (row >> 1)) & 3);
}

// bijective XCD-chunking remap (m204): physical dispatch id p -> logical work
// id such that XCD (p%8) owns a contiguous logical chunk.
__device__ __forceinline__ int xcd_swz(int flat, int nwg) {
    int q = nwg >> 3, r = nwg & 7;
    int x = flat & 7, i = flat >> 3;
    return (x < r ? x * (q + 1) : r * (q + 1) + (x - r) * q) + i;
}

// ---- staging helper for fp32 A: 8 floats -> 8 bf16 at LDS slot ----
__device__ __forceinline__ void stage8f(const float* p, u16* d) {
    float4 v0 = *(const float4*)p;
    float4 v1 = *(const float4*)(p + 4);
    ushort4 a; a.x = f2b(v0.x); a.y = f2b(v0.y); a.z = f2b(v0.z); a.w = f2b(v0.w);
    ushort4 b; b.x = f2b(v1.x); b.y = f2b(v1.y); b.z = f2b(v1.z); b.w = f2b(v1.w);
    *(ushort4*)d = a;
    *(ushort4*)(d + 4) = b;
}

// ---- stage a [LC x 256] u16 tile (row stride = ld u16) into linear LDS ----
__device__ __forceinline__ void stage_tile256(
    const u16* __restrict__ g, int row0, int ld, int e0, u16* lds, int t)
{
    const int wv = t >> 6, ln = t & 63;
    #pragma unroll
    for (int iss = 0; iss < 4; iss++) {
        int row = wv * 8 + iss * 2;
        const u16* src = g + (size_t)(row0 + row + (ln >> 5)) * ld
                       + e0 + (ln & 31) * 8;
        async16(src, &lds[row * 256]);
    }
}

// ---- one-shot fp32->bf16 convert of x, merge_w, and both dirs' weights ----
__global__ __launch_bounds__(256) void cvt_all_kernel(
    const float* __restrict__ s0, const float* __restrict__ s1,
    const float* __restrict__ s2, const float* __restrict__ s3,
    const float* __restrict__ s4, const float* __restrict__ s5,
    const float* __restrict__ s6, const float* __restrict__ s7,
    const float* __restrict__ s8, const float* __restrict__ s9,
    u16* __restrict__ d0, u16* __restrict__ d1, u16* __restrict__ d2,
    u16* __restrict__ d3, u16* __restrict__ d4, u16* __restrict__ d5,
    u16* __restrict__ d6, u16* __restrict__ d7, u16* __restrict__ d8,
    u16* __restrict__ d9)
{
    int i = blockIdx.x * 256 + threadIdx.x;
    const float* s; u16* d;
    if (i < N4_X) { s = s0; d = d0; }                    // x
    else if ((i -= N4_X) < N4_MW) { s = s1; d = d1; }    // merge_w
    else if ((i -= N4_MW) < N4_IN) { s = s2; d = d2; }   // in0
    else if ((i -= N4_IN) < N4_XP) { s = s3; d = d3; }   // xp0
    else if ((i -= N4_XP) < N4_DT) { s = s4; d = d4; }   // dt0
    else if ((i -= N4_DT) < N4_OUT) { s = s5; d = d5; }  // out0
    else if ((i -= N4_OUT) < N4_IN) { s = s6; d = d6; }  // in1
    else if ((i -= N4_IN) < N4_XP) { s = s7; d = d7; }   // xp1
    else if ((i -= N4_XP) < N4_DT) { s = s8; d = d8; }   // dt1
    else if ((i -= N4_DT) < N4_OUT) { s = s9; d = d9; }  // out1
    else return;
    float4 v = ((const float4*)s)[i];
    ushort4 o; o.x = f2b(v.x); o.y = f2b(v.y); o.z = f2b(v.z); o.w = f2b(v.w);
    ((ushort4*)d)[i] = o;
}

// ===========================================================================
// 256x256-tile 8-phase GEMM (HK-style schedule) for step 1. See R5 lesson:
// this beats the BN=128 2-phase loop at this shape (FETCH 24.6 vs 69.7 MB).
// ===========================================================================
__global__ __launch_bounds__(512) void gemm256_dual(
    const u16* __restrict__ A,
    const u16* __restrict__ Wd0, const u16* __restrict__ Wd1,
    u16* __restrict__ Cd0, u16* __restrict__ Cd1,
    int lda, int ldw, int ldc, int K)
{
    __shared__ u16 lds[65536];                 // 128 KiB
    const int t    = threadIdx.x;
    const int lane = t & 63;
    const int w    = t >> 6;
    const int wr   = w >> 2;                   // 0..1
    const int wc   = w & 3;                    // 0..3
    const int fm   = lane & 15;
    const int q    = lane >> 4;
    const int dir  = blockIdx.z;
    const u16* W   = dir ? Wd1 : Wd0;
    u16* C         = dir ? Cd1 : Cd0;
    const int m0   = blockIdx.y * 256;
    const int n0   = blockIdx.x * 256;
    const int T    = K >> 6;                   // K-tiles (16 for K=1024)

    // ds_read u16 offsets within a 128x64 half (slot*8 u16)
    int offA[4][2], offW[2][2];
    #pragma unroll
    for (int mi = 0; mi < 4; mi++)
        #pragma unroll
        for (int kk = 0; kk < 2; kk++) {
            int r = wr * 64 + mi * 16 + fm;
            int j = kk * 4 + q;
            offA[mi][kk] = (r * 8 + ((j + r) & 7)) * 8;
        }
    #pragma unroll
    for (int ni = 0; ni < 2; ni++)
        #pragma unroll
        for (int kk = 0; kk < 2; kk++) {
            int r = wc * 32 + ni * 16 + fm;
            int j = kk * 4 + q;
            offW[ni][kk] = (r * 8 + ((j + r) & 7)) * 8;
        }

    // staging decomposition: slot = p*512 + t; r = slot>>3; j = ((slot&7)-r)&7
    int sr[2], sj[2];
    #pragma unroll
    for (int p = 0; p < 2; p++) {
        int slot = p * 512 + t;
        sr[p] = slot >> 3;
        sj[p] = ((slot & 7) - sr[p]) & 7;
    }
    const int ldsWaveBase = (t & ~63) * 8;     // u16; p adds 4096

#define STAGE(G, ld, row0, kcol, dstBase)                                    \
    { _Pragma("unroll")                                                      \
      for (int p = 0; p < 2; p++) {                                          \
          const u16* src_ = (G) + (size_t)((row0) + sr[p]) * (ld)            \
                          + (kcol) + sj[p] * 8;                              \
          async16(src_, &lds[(dstBase) + p * 4096 + ldsWaveBase]);           \
      } }

    f32x4 acc[2][2][4][2] = {};
    bf16x8 af[4][2], wf[2][2];

#define DSREAD_A(mh, cur)                                                    \
    { _Pragma("unroll")                                                      \
      for (int mi = 0; mi < 4; mi++)                                         \
          _Pragma("unroll")                                                  \
          for (int kk = 0; kk < 2; kk++)                                     \
              af[mi][kk] = *(const bf16x8*)&lds[(cur) + (mh) * 8192          \
                                                + offA[mi][kk]]; }
#define DSREAD_W(nh, cur)                                                    \
    { _Pragma("unroll")                                                      \
      for (int ni = 0; ni < 2; ni++)                                         \
          _Pragma("unroll")                                                  \
          for (int kk = 0; kk < 2; kk++)                                     \
              wf[ni][kk] = *(const bf16x8*)&lds[(cur) + 16384 + (nh) * 8192  \
                                                + offW[ni][kk]]; }
#define MFMA16(mh, nh)                                                       \
    { __builtin_amdgcn_s_setprio(1);                                         \
      _Pragma("unroll")                                                      \
      for (int mi = 0; mi < 4; mi++)                                         \
          _Pragma("unroll")                                                  \
          for (int ni = 0; ni < 2; ni++)                                     \
              _Pragma("unroll")                                              \
              for (int kk = 0; kk < 2; kk++)                                 \
                  acc[mh][nh][mi][ni] =                                      \
                      __builtin_amdgcn_mfma_f32_16x16x32_bf16(               \
                          af[mi][kk], wf[ni][kk], acc[mh][nh][mi][ni],       \
                          0, 0, 0);                                          \
      __builtin_amdgcn_s_setprio(0); }

#define WAITVM(n) asm volatile("s_waitcnt vmcnt(" #n ")" ::: "memory")
#define BAR() __builtin_amdgcn_s_barrier()

    // prologue: tile 0 -> buf0; issue order Ah0, Wh0, Wh1, Ah1
    STAGE(A, lda, m0,       0, 0);
    STAGE(W, ldw, n0,       0, 16384);
    STAGE(W, ldw, n0 + 128, 0, 16384 + 8192);
    STAGE(A, lda, m0 + 128, 0, 8192);
    WAITVM(4);                    // Ah0,Wh0 landed; Wh1,Ah1 in flight
    BAR();

    for (int tt = 0; tt < T - 1; ++tt) {
        const int cur = (tt & 1) * 32768;
        const int nxt = 32768 - cur;
        const int kn  = (tt + 1) << 6;
        // phase 0: quadrant (0,0); stage Ah0(t+1); guard Wh1(t) for p1
        DSREAD_A(0, cur); DSREAD_W(0, cur);
        STAGE(A, lda, m0, kn, nxt);
        WAITVM(4);
        BAR();
        MFMA16(0, 0);
        BAR();
        // phase 1: quadrant (0,1) (A-frags reused); stage Wh0(t+1); guard Ah1(t)
        DSREAD_W(1, cur);
        STAGE(W, ldw, n0, kn, nxt + 16384);
        WAITVM(4);
        BAR();
        MFMA16(0, 1);
        BAR();
        // phase 2: quadrant (1,1) (W-frags reused); stage Wh1(t+1); no wait
        DSREAD_A(1, cur);
        STAGE(W, ldw, n0 + 128, kn, nxt + 16384 + 8192);
        BAR();
        MFMA16(1, 1);
        BAR();
        // phase 3: quadrant (1,0); stage Ah1(t+1); guard Ah0,Wh0(t+1) for next
        DSREAD_W(0, cur);
        STAGE(A, lda, m0 + 128, kn, nxt + 8192);
        WAITVM(4);
        BAR();
        MFMA16(1, 0);
        BAR();
    }
    // tail tile T-1 (no staging; drain allowed)
    {
        const int cur = ((T - 1) & 1) * 32768;
        DSREAD_A(0, cur); DSREAD_W(0, cur);
        WAITVM(2);                 // Wh1 ready for p1
        BAR();
        MFMA16(0, 0);
        BAR();
        DSREAD_W(1, cur);
        WAITVM(0);                 // Ah1 ready for p2
        BAR();
        MFMA16(0, 1);
        BAR();
        DSREAD_A(1, cur);
        BAR();
        MFMA16(1, 1);
        BAR();
        DSREAD_W(0, cur);
        MFMA16(1, 0);
    }
#undef STAGE
#undef DSREAD_A
#undef DSREAD_W
#undef MFMA16
#undef WAITVM
#undef BAR

    // epilogue: C/D layout col=lane&15, row=(lane>>4)*4+reg; bf16 store
    #pragma unroll
    for (int mh = 0; mh < 2; mh++)
        #pragma unroll
        for (int mi = 0; mi < 4; mi++)
            #pragma unroll
            for (int rr = 0; rr < 4; rr++) {
                int gm = m0 + mh * 128 + wr * 64 + mi * 16 + q * 4 + rr;
                int om = gm;
                if (dir == 1) {                      // flip within batch SEQ
                    om = (gm & ~(SEQ - 1)) | ((SEQ - 1) - (gm & (SEQ - 1)));
                }
                u16* crow = C + (size_t)om * ldc;
                #pragma unroll
                for (int nh = 0; nh < 2; nh++)
                    #pragma unroll
                    for (int ni = 0; ni < 2; ni++) {
                        int gn = n0 + nh * 128 + wc * 32 + ni * 16 + fm;
                        crow[gn] = f2b(acc[mh][nh][mi][ni][rr]);
                    }
            }
}

// ---------------- dual-direction MFMA GEMM (steps 3,4,6,7) -----------------
// 2-PHASE double-buffered LDS (R9/R12-proven; R10 3-deep pipeline, R11 broad
// split-K, R13 step-6 split-K all regressed — journaled FAILED).
// SWZ: bijective XCD remap (T1/m204).
template <typename TA, typename TC, int ACT, bool DUAL, bool FLIP1, int NSPLIT,
          int BN, bool SWZ>
__global__ __launch_bounds__(256) void mfma_gemm(
    const TA* __restrict__ A0, const TA* __restrict__ A1, int lda,
    const u16* __restrict__ W0, const u16* __restrict__ W1, int ldw,
    const float* __restrict__ bias0, const float* __restrict__ bias1,
    TC* __restrict__ C0, TC* __restrict__ C1, int ldc,
    int M, int N, int K)
{
    constexpr int NF = BN / 32;          // n-fragments per wave (2 or 4)
    __shared__ u16 As[2][128 * 32];
    __shared__ u16 Ws[2][BN * 32];

    int bx = blockIdx.x, by = blockIdx.y, bz = blockIdx.z;
    if (SWZ) {
        const int gx = gridDim.x, gy = gridDim.y;
        const int nwg = gx * gy * gridDim.z;
        int flat = (blockIdx.z * gy + blockIdx.y) * gx + blockIdx.x;
        flat = xcd_swz(flat, nwg);
        bx = flat % gx;
        int rest = flat / gx;
        by = rest % gy;
        bz = rest / gy;
    }

    const int z = bz;
    const int dir = DUAL ? (z / NSPLIT) : 0;
    const int split = z % NSPLIT;
    const TA* A = dir ? A1 : A0;
    const u16* W = dir ? W1 : W0;
    const float* bias = dir ? bias1 : bias0;
    TC* C = dir ? C1 : C0;
    if (NSPLIT > 1) C += (size_t)split * M * ldc;
    const int kseg = K / NSPLIT;
    const int kbeg = split * kseg;
    const int kiters = kseg / 32;

    const int t = threadIdx.x;
    const int wave = t >> 6;
    const int lane = t & 63;
    const int wm = (wave & 1) * 64;
    const int wn = (wave >> 1) * (BN / 2);
    const int fm = lane & 15;
    const int q  = lane >> 4;
    const int m0 = by * 128;
    const int n0 = bx * BN;

    auto stage_tile = [&](int k0, int b) {
        if constexpr (__is_same(TA, u16)) {
            #pragma unroll
            for (int p = 0; p < 2; p++) {
                int i = p * 256 + wave * 64 + lane;
                int r = i >> 2;
                int j = ((i & 3) - (r >> 1)) & 3;
                async16(A + (size_t)(m0 + r) * lda + k0 + j * 8,
                        &As[b][(size_t)(p * 256 + wave * 64) * 8]);
            }
        } else {
            #pragma unroll
            for (int p = 0; p < 2; p++) {
                int i = p * 256 + t;
                int r = i >> 2;
                int j = ((i & 3) - (r >> 1)) & 3;
                stage8f(A + (size_t)(m0 + r) * lda + k0 + j * 8,
                        &As[b][(size_t)i * 8]);
            }
        }
        #pragma unroll
        for (int p = 0; p < BN / 64; p++) {
            int i = p * 256 + wave * 64 + lane;
            int r = i >> 2;
            int j = ((i & 3) - (r >> 1)) & 3;
            int gr = n0 + r;
            if (gr >= N) gr = N - 1;   // clamp (junk discarded at store)
            async16(W + (size_t)gr * ldw + k0 + j * 8,
                    &Ws[b][(size_t)(p * 256 + wave * 64) * 8]);
        }
    };

    f32x4 acc[4][NF] = {};

    stage_tile(kbeg, 0);
    __syncthreads();

    for (int ii = 0; ii < kiters; ii++) {
        const int cur = ii & 1;
        if (ii + 1 < kiters)
            stage_tile(kbeg + (ii + 1) * 32, cur ^ 1);   // prefetch next tile

        bf16x8 af[4], wf[NF];
        #pragma unroll
        for (int mi = 0; mi < 4; mi++)
            af[mi] = *(const bf16x8*)
                &As[cur][(size_t)lds_slot(wm + mi * 16 + fm, q) * 8];
        #pragma unroll
        for (int ni = 0; ni < NF; ni++)
            wf[ni] = *(const bf16x8*)
                &Ws[cur][(size_t)lds_slot(wn + ni * 16 + fm, q) * 8];
        #pragma unroll
        for (int mi = 0; mi < 4; mi++)
            #pragma unroll
            for (int ni = 0; ni < NF; ni++)
                acc[mi][ni] = __builtin_amdgcn_mfma_f32_16x16x32_bf16(
                    af[mi], wf[ni], acc[mi][ni], 0, 0, 0);

        __syncthreads();   // vmcnt(0)+lgkmcnt(0)+barrier: next buf ready,
                           // cur buf fully consumed by all waves
    }

    // C/D layout: col = lane&15, row = (lane>>4)*4 + reg
    const int rb = q * 4;
    const int cc = fm;
    #pragma unroll
    for (int mi = 0; mi < 4; mi++) {
        #pragma unroll
        for (int r = 0; r < 4; r++) {
            int gm = m0 + wm + mi * 16 + rb + r;
            int om = gm;
            if (FLIP1 && dir == 1) {
                int bb = gm / SEQ, l = gm % SEQ;
                om = bb * SEQ + (SEQ - 1 - l);
            }
            #pragma unroll
            for (int ni = 0; ni < NF; ni++) {
                int gn = n0 + wn + ni * 16 + cc;
                if (gn < N) {
                    float v = acc[mi][ni][r];
                    if (ACT == 1) v = softplus_fast(v + bias[gn]);
                    stf(C, (size_t)om * ldc + gn, v);
                }
            }
        }
    }
}

// ---- split-K combines ----
__global__ __launch_bounds__(256) void combine_dbl_kernel(
    const float* __restrict__ par, float* __restrict__ dbl)
{
    int i4 = blockIdx.x * 256 + threadIdx.x;   // [0, 2*MM*NDBL/4)
    const int per = (MM * NDBL) / 4;           // 49152
    int dir = (i4 >= per) ? 1 : 0;
    int j4 = i4 - dir * per;
    const float* p = par + (size_t)dir * 4 * MM * NDBL;
    f32x4 s = {0.f, 0.f, 0.f, 0.f};
    #pragma unroll
    for (int k = 0; k < 4; k++)
        s += *(const f32x4*)&p[(size_t)k * MM * NDBL + (size_t)j4 * 4];
    *(f32x4*)&dbl[(size_t)dir * MM * NDBL + (size_t)j4 * 4] = s;
}

__global__ __launch_bounds__(256) void combine_out_kernel(
    const float* __restrict__ p0, float* __restrict__ out)
{
    int i4 = blockIdx.x * 256 + threadIdx.x;   // [0, MM*DM/4)
    const float* p1 = p0 + (size_t)MM * DM;
    f32x4 a = *(const f32x4*)&p0[(size_t)i4 * 4];
    f32x4 b = *(const f32x4*)&p1[(size_t)i4 * 4];
    *(f32x4*)&out[(size_t)i4 * 4] = a + b;
}

// ---- conv + silu, both dirs, 4 channels/thread; xz is bf16 ----
__global__ __launch_bounds__(256) void conv_silu_kernel(
    const u16* __restrict__ xz,
    const float* __restrict__ cw0, const float* __restrict__ cw1,
    const float* __restrict__ cb0, const float* __restrict__ cb1,
    u16* __restrict__ xcb)
{
    int i4 = blockIdx.x * 256 + threadIdx.x;    // [0, 2*MM*DI/4)
    const int per = MM * DI / 4;
    int dir = (i4 >= per) ? 1 : 0;
    int rem = i4 - dir * per;
    int e4 = rem & (DI / 4 - 1);
    int bl = rem / (DI / 4);
    int l = bl & (SEQ - 1);
    int e = e4 * 4;
    const u16* xz_d = xz + (size_t)dir * MM * 2 * DI;
    const float* cw = dir ? cw1 : cw0;
    const float* cb = dir ? cb1 : cb0;
    f32x4 cwv[4];
    #pragma unroll
    for (int i = 0; i < 4; i++) cwv[i] = *(const f32x4*)&cw[(e + i) * DC];
    f32x4 acc = *(const f32x4*)&cb[e];
    #pragma unroll
    for (int k = 0; k < DC; k++) {
        int ll = l + k - (DC - 1);
        if (ll >= 0) {
            ushort4 xv = *(const ushort4*)&xz_d[(size_t)(bl - l + ll) * (2 * DI) + e];
            acc[0] += cwv[0][k] * b2f(xv.x);
            acc[1] += cwv[1][k] * b2f(xv.y);
            acc[2] += cwv[2][k] * b2f(xv.z);
            acc[3] += cwv[3][k] * b2f(xv.w);
        }
    }
    ushort4 o;
    #pragma unroll
    for (int i = 0; i < 4; i++) {
        float s = silu_fast(acc[i]);
        ((u16*)&o)[i] = f2b(s);
    }
    ((ushort4*)xcb)[(size_t)dir * per + rem] = o;
}

// ---- Chunked scan, both dirs, n-in-registers; xc is bf16 ----
// P-ELIMINATION (R6) + POWER FAST PATH (R7) + LDS INPUT STAGING (R9).
// grid (NC, DI/256, 2*BSZ); z: dir = z>>1, b = z&1.
__global__ __launch_bounds__(256) void scan_pass1(
    const float* __restrict__ dbl,
    const u16*  __restrict__ xc,
    const u16*  __restrict__ delta,
    const float* __restrict__ Alog0, const float* __restrict__ Alog1,
    float* __restrict__ Qout, float* __restrict__ Dout)
{
    __shared__ float sB[LC][16];
    __shared__ u16 sD[LC * 256];     // delta tile, 16 KB
    __shared__ u16 sX[LC * 256];     // xc tile,    16 KB
    const int t = threadIdx.x;
    const int c = blockIdx.x;
    const int dir = blockIdx.z >> 1;
    const int b = blockIdx.z & 1;
    const int ey = blockIdx.y;
    const int e = ey * 256 + t;
    const int row0 = b * SEQ + c * LC;
    const float* dbl_d = dbl + (size_t)dir * MM * NDBL;
    const u16* xc_d = xc + (size_t)dir * MM * DI;
    const u16* delta_d = delta + (size_t)dir * MM * DI;
    const float* A_log = dir ? Alog1 : Alog0;
    float* Q_d = Qout + (size_t)dir * BSZ * NC * DI * DS;
    float* D_d = Dout + (size_t)dir * BSZ * NC * DI;

    stage_tile256(delta_d, row0, DI, ey * 256, sD, t);
    stage_tile256(xc_d,    row0, DI, ey * 256, sX, t);

    if (t < LC * 4) {
        int row = t >> 2, col = (t & 3) * 4;
        *(f32x4*)&sB[row][col] =
            *(const f32x4*)&dbl_d[(size_t)(row0 + row) * NDBL + DR + col];
    }

    f32x4 Aen[4], Q[4];
    #pragma unroll
    for (int g = 0; g < 4; g++) {
        f32x4 a = *(const f32x4*)&A_log[(size_t)e * DS + g * 4];
        #pragma unroll
        for (int j = 0; j < 4; j++) Aen[g][j] = -fexp(a[j]);
        Q[g] = f32x4{0.f, 0.f, 0.f, 0.f};
    }
    const float a0 = Aen[0][0];
    bool pw = true;
    #pragma unroll
    for (int g = 0; g < 4; g++)
        #pragma unroll
        for (int j = 0; j < 4; j++)
            pw = pw && (fabsf(Aen[g][j] - (float)(g * 4 + j + 1) * a0)
                        <= 1e-4f * fabsf(Aen[g][j]));
    __syncthreads();   // staging (vmcnt) + sB visible to all

    float dsum = 0.f;
    if (pw) {
        for (int i = 0; i < LC; i++) {
            float dv = b2f(sD[i * 256 + t]);
            float xv = b2f(sX[i * 256 + t]);
            float du = dv * xv;
            dsum += dv;
            float e1 = fexp(dv * a0);
            float e2 = e1 * e1, e3 = e2 * e1, e4 = e2 * e2;
            float e8 = e4 * e4, e12 = e8 * e4;
            float lo[4] = {e1, e2, e3, e4};
            float Eg[4] = {1.f, e4, e8, e12};
            #pragma unroll
            for (int g = 0; g < 4; g++) {
                f32x4 Bv = *(const f32x4*)&sB[i][g * 4];
                #pragma unroll
                for (int j = 0; j < 4; j++) {
                    float dA = (g == 0) ? lo[j] : Eg[g] * lo[j];
                    Q[g][j] = dA * Q[g][j] + du * Bv[j];
                }
            }
        }
    } else {
        for (int i = 0; i < LC; i++) {
            float dv = b2f(sD[i * 256 + t]);
            float xv = b2f(sX[i * 256 + t]);
            float du = dv * xv;
            dsum += dv;
            #pragma unroll
            for (int g = 0; g < 4; g++) {
                f32x4 Bv = *(const f32x4*)&sB[i][g * 4];
                #pragma unroll
                for (int j = 0; j < 4; j++) {
                    float dA = fexp(dv * Aen[g][j]);
                    Q[g][j] = dA * Q[g][j] + du * Bv[j];
                }
            }
        }
    }
    size_t base = ((size_t)(b * NC + c) * DI + e) * DS;
    #pragma unroll
    for (int g = 0; g < 4; g++)
        *(f32x4*)&Q_d[base + g * 4] = Q[g];
    D_d[(size_t)(b * NC + c) * DI + e] = dsum;
}

// pass2: stitch chunks. h_{c+1} = exp(Aen_j * Dsum[c]) * h_c + Q[c].
__global__ __launch_bounds__(256) void scan_pass2(
    const float* __restrict__ Q, const float* __restrict__ Dsum,
    const float* __restrict__ Alog0, const float* __restrict__ Alog1,
    float* __restrict__ H0)
{
    const int gid = blockIdx.x * 256 + threadIdx.x;  // [0, 2*BSZ*DI*DS)
    const int dir = gid >> 16;
    const int loc = gid & 65535;
    const int b = loc >> 15;
    const int en = loc & (DI * DS - 1);              // e*DS + j
    const int e = en >> 4;
    const float* A_log = dir ? Alog1 : Alog0;
    const float aen = -fexp(A_log[en]);
    size_t doff = (size_t)dir * BSZ * NC * DI * DS;
    size_t doffD = (size_t)dir * BSZ * NC * DI;
    float h = 0.f;
    for (int c = 0; c < NC; c++) {
        size_t idx = doff + ((size_t)(b * NC + c) * DI * DS) + en;
        H0[idx] = h;
        float Dc = Dsum[doffD + (size_t)(b * NC + c) * DI + e];
        h = fexp(Dc * aen) * h + Q[idx];
    }
}

// pass3: replay chunk; writes gated y IN-PLACE over delta; z is bf16.
// Inputs (delta, xc, z) staged to LDS up front (R9).
__global__ __launch_bounds__(256) void scan_pass3(
    const float* __restrict__ dbl,
    const u16*  __restrict__ xc,
    const u16*  __restrict__ xz,
    u16* delta_y,
    const float* __restrict__ Alog0, const float* __restrict__ Alog1,
    const float* __restrict__ Dp0, const float* __restrict__ Dp1,
    const float* __restrict__ H0)
{
    __shared__ float sBC[LC][32];
    __shared__ u16 sD[LC * 256];     // delta tile, 16 KB
    __shared__ u16 sX[LC * 256];     // xc tile,    16 KB
    __shared__ u16 sZ[LC * 256];     // z tile,     16 KB
    const int t = threadIdx.x;
    const int c = blockIdx.x;
    const int dir = blockIdx.z >> 1;
    const int b = blockIdx.z & 1;
    const int ey = blockIdx.y;
    const int e = ey * 256 + t;
    const int row0 = b * SEQ + c * LC;
    const float* dbl_d = dbl + (size_t)dir * MM * NDBL;
    const u16* xc_d = xc + (size_t)dir * MM * DI;
    const u16* xz_d = xz + (size_t)dir * MM * 2 * DI;
    u16* dy_d = delta_y + (size_t)dir * MM * DI;
    const float* A_log = dir ? Alog1 : Alog0;
    const float* Dp = dir ? Dp1 : Dp0;
    const float* H0_d = H0 + (size_t)dir * BSZ * NC * DI * DS;

    stage_tile256(dy_d, row0, DI, ey * 256, sD, t);
    stage_tile256(xc_d, row0, DI, ey * 256, sX, t);
    stage_tile256(xz_d, row0, 2 * DI, DI + ey * 256, sZ, t);  // z half

    {
        int row = t >> 3, col = (t & 7) * 4;
        *(f32x4*)&sBC[row][col] =
            *(const f32x4*)&dbl_d[(size_t)(row0 + row) * NDBL + DR + col];
    }

    f32x4 Aen[4], h[4];
    size_t base = ((size_t)(b * NC + c) * DI + e) * DS;
    #pragma unroll
    for (int g = 0; g < 4; g++) {
        f32x4 a = *(const f32x4*)&A_log[(size_t)e * DS + g * 4];
        #pragma unroll
        for (int j = 0; j < 4; j++) Aen[g][j] = -fexp(a[j]);
        h[g] = *(const f32x4*)&H0_d[base + g * 4];
    }
    const float Dv = Dp[e];
    const float a0 = Aen[0][0];
    bool pw = true;
    #pragma unroll
    for (int g = 0; g < 4; g++)
        #pragma unroll
        for (int j = 0; j < 4; j++)
            pw = pw && (fabsf(Aen[g][j] - (float)(g * 4 + j + 1) * a0)
                        <= 1e-4f * fabsf(Aen[g][j]));
    __syncthreads();   // staging (vmcnt) + sBC visible to all

    if (pw) {
        for (int i = 0; i < LC; i++) {
            float dv = b2f(sD[i * 256 + t]);
            float xv = b2f(sX[i * 256 + t]);
            float zv = b2f(sZ[i * 256 + t]);
            float du = dv * xv;
            float e1 = fexp(dv * a0);
            float e2 = e1 * e1, e3 = e2 * e1, e4 = e2 * e2;
            float e8 = e4 * e4, e12 = e8 * e4;
            float lo[4] = {e1, e2, e3, e4};
            float Eg[4] = {1.f, e4, e8, e12};
            f32x4 pv = {0.f, 0.f, 0.f, 0.f};
            #pragma unroll
            for (int g = 0; g < 4; g++) {
                f32x4 Bv = *(const f32x4*)&sBC[i][g * 4];
                f32x4 Cv = *(const f32x4*)&sBC[i][16 + g * 4];
                #pragma unroll
                for (int j = 0; j < 4; j++) {
                    float dA = (g == 0) ? lo[j] : Eg[g] * lo[j];
                    h[g][j] = dA * h[g][j] + du * Bv[j];
                    pv[j] += h[g][j] * Cv[j];
                }
            }
            float p = pv[0] + pv[1] + pv[2] + pv[3];
            float y = (p + xv * Dv) * silu_fast(zv);
            dy_d[(size_t)(row0 + i) * DI + e] = f2b(y);
        }
    } else {
        for (int i = 0; i < LC; i++) {
            float dv = b2f(sD[i * 256 + t]);
            float xv = b2f(sX[i * 256 + t]);
            float zv = b2f(sZ[i * 256 + t]);
            float du = dv * xv;
            f32x4 pv = {0.f, 0.f, 0.f, 0.f};
            #pragma unroll
            for (int g = 0; g < 4; g++) {
                f32x4 Bv = *(const f32x4*)&sBC[i][g * 4];
                f32x4 Cv = *(const f32x4*)&sBC[i][16 + g * 4];
                #pragma unroll
                for (int j = 0; j < 4; j++) {
                    float dA = fexp(dv * Aen[g][j]);
                    h[g][j] = dA * h[g][j] + du * Bv[j];
                    pv[j] += h[g][j] * Cv[j];
                }
            }
            float p = pv[0] + pv[1] + pv[2] + pv[3];
            float y = (p + xv * Dv) * silu_fast(zv);
            dy_d[(size_t)(row0 + i) * DI + e] = f2b(y);
        }
    }
}

extern "C" void kernel_launch(void* const* d_in, const int* in_sizes, int n_in,
                              void* d_out, int out_size, void* d_ws, size_t ws_size,
                              hipStream_t stream)
{
    const float* x = (const float*)d_in[0];
    const float* in_p[2]  = {(const float*)d_in[1],  (const float*)d_in[10]};
    const float* conv_w[2]= {(const float*)d_in[2],  (const float*)d_in[11]};
    const float* conv_b[2]= {(const float*)d_in[3],  (const float*)d_in[12]};
    const float* x_p[2]   = {(const float*)d_in[4],  (const float*)d_in[13]};
    const float* dt_w[2]  = {(const float*)d_in[5],  (const float*)d_in[14]};
    const float* dt_b[2]  = {(const float*)d_in[6],  (const float*)d_in[15]};
    const float* A_log[2] = {(const float*)d_in[7],  (const float*)d_in[16]};
    const float* Dp[2]    = {(const float*)d_in[8],  (const float*)d_in[17]};
    const float* out_p[2] = {(const float*)d_in[9],  (const float*)d_in[18]};
    const float* merge_w  = (const float*)d_in[19];
    float* out = (float*)d_out;

    // ---- workspace layout (element units) ----
    float* ws = (float*)d_ws;
    float* ws_dbl = ws;                                    // 2 * MM*NDBL f
    float* ws_Q   = ws_dbl + (size_t)2 * MM * NDBL;        // 2 * BSZ*NC*DI*DS f
    float* ws_D   = ws_Q   + (size_t)2 * BSZ * NC * DI * DS; // 2*BSZ*NC*DI f
    float* ws_H0  = ws_D   + (size_t)2 * BSZ * NC * DI;
    u16* ws_xz    = (u16*)(ws_H0 + (size_t)2 * BSZ * NC * DI * DS); // 2*MM*2DI u16
    u16* ws_delta = ws_xz    + (size_t)2 * MM * 2 * DI;    // 2*MM*DI u16
    u16* ws_xcb   = ws_delta + (size_t)2 * MM * DI;        // 2*MM*DI u16
    u16* ws_cat   = ws_xcb   + (size_t)2 * MM * DI;        // MM*2DM u16
    u16* ws_xbf   = ws_cat   + (size_t)MM * 2 * DM;        // MM*DM u16
    u16* wbf_mw   = ws_xbf   + (size_t)MM * DM;            // DM*2DM u16
    u16* wbf0     = wbf_mw   + (size_t)DM * 2 * DM;        // WBF_SZ u16
    u16* wbf1     = wbf0     + WBF_SZ;                     // WBF_SZ u16
    // split-K partials alias Q (dead when used): step-3 needs 1.57M f,
    // step-7 needs 4.19M f; Q region = 4.19M f -> fits.
    float* ws_par = ws_Q;

    // 0) one-shot convert: x, merge_w, all weights (both dirs)
    cvt_all_kernel<<<(N4_TOTAL + 255) / 256, 256, 0, stream>>>(
        x, merge_w, in_p[0], x_p[0], dt_w[0], out_p[0],
        in_p[1], x_p[1], dt_w[1], out_p[1],
        ws_xbf, wbf_mw,
        wbf0, wbf0 + O_XP, wbf0 + O_DT, wbf0 + O_OUT,
        wbf1, wbf1 + O_XP, wbf1 + O_DT, wbf1 + O_OUT);

    // 1) xz = x @ in_proj^T (both dirs; dir1 rows flipped) — 256x256 8-phase,
    //    bf16 out (R5 lesson: this structure wins at this shape).
    gemm256_dual<<<dim3(16, 8, 2), 512, 0, stream>>>(
        ws_xbf, wbf0, wbf1,
        ws_xz, ws_xz + (size_t)MM * 2 * DI,
        DM, DM, 2 * DI, DM);

    // 2) conv + silu (both dirs, 4-wide, bf16 in/out)
    conv_silu_kernel<<<(2 * MM * DI / 4) / 256, 256, 0, stream>>>(
        ws_xz, conv_w[0], conv_w[1], conv_b[0], conv_b[1], ws_xcb);

    // 3) dbl = xc @ x_proj^T  (N=96, split-K4, both dirs, XCD-swizzled)
    mfma_gemm<u16, float, 0, true, false, 4, 64, true>
        <<<dim3(2, 16, 8), 256, 0, stream>>>(
        ws_xcb, ws_xcb + (size_t)MM * DI, DI,
        wbf0 + O_XP, wbf1 + O_XP, DI, nullptr, nullptr,
        ws_par, ws_par + (size_t)4 * MM * NDBL, NDBL, MM, NDBL, DI);
    combine_dbl_kernel<<<(2 * MM * NDBL / 4) / 256, 256, 0, stream>>>(ws_par, ws_dbl);

    // 4) delta = softplus(dt @ dt_w^T + dt_b) -> bf16 (K=64, fp32 A, both dirs)
    mfma_gemm<float, u16, 1, true, false, 1, 64, true>
        <<<dim3(32, 16, 2), 256, 0, stream>>>(
        ws_dbl, ws_dbl + (size_t)MM * NDBL, NDBL,
        wbf0 + O_DT, wbf1 + O_DT, DR, dt_b[0], dt_b[1],
        ws_delta, ws_delta + (size_t)MM * DI, DI, MM, DI, DR);

    // 5) chunked scan (both dirs); P eliminated via chunk delta-sum;
    //    power fast path for dA; LDS-staged inputs; pass3 writes y over delta
    {
        dim3 grid(NC, DI / 256, 2 * BSZ);
        scan_pass1<<<grid, 256, 0, stream>>>(ws_dbl, ws_xcb, ws_delta,
                                             A_log[0], A_log[1], ws_Q, ws_D);
        scan_pass2<<<(2 * BSZ * DI * DS) / 256, 256, 0, stream>>>(
            ws_Q, ws_D, A_log[0], A_log[1], ws_H0);
        scan_pass3<<<grid, 256, 0, stream>>>(ws_dbl, ws_xcb, ws_xz, ws_delta,
                                             A_log[0], A_log[1], Dp[0], Dp[1], ws_H0);
    }

    // 6) cat = y @ out_proj^T — BN=64, 512 blocks (2/CU), XCD-swizzled,
    //    2-phase pipelined; bf16 cat written directly (dir-1 cols at +DM).
    mfma_gemm<u16, u16, 0, true, true, 1, 64, true>
        <<<dim3(16, 16, 2), 256, 0, stream>>>(
        ws_delta, ws_delta + (size_t)MM * DI, DI,
        wbf0 + O_OUT, wbf1 + O_OUT, DI, nullptr, nullptr,
        ws_cat, ws_cat + DM, 2 * DM, MM, DM, DI);

    // 7) out = cat @ merge_w^T — BN=64, split-K2 (512 blocks), XCD-swizzled
    mfma_gemm<u16, float, 0, false, false, 2, 64, true>
        <<<dim3(16, 16, 2), 256, 0, stream>>>(
        ws_cat, ws_cat, 2 * DM, wbf_mw, wbf_mw, 2 * DM, nullptr, nullptr,
        ws_par, ws_par, DM, MM, DM, 2 * DM);
    combine_out_kernel<<<(MM * DM / 4) / 256, 256, 0, stream>>>(ws_par, out);
}